// Round 1
// baseline (1121.619 us; speedup 1.0000x reference)
//
#include <hip/hip_runtime.h>

#define BN 100000
#define DD 128
#define EN 500000
#define NM 4096
#define NROWS (BN + NM)     // 104096
#define NCOPY 8

// ws layout (in floats)
#define LEN_H ((size_t)NROWS * DD)            // 13,324,288
#define OFF_ACC LEN_H
#define LEN_ACC ((size_t)NCOPY * NM * DD)     // 4,194,304
#define OFF_SLOTS (OFF_ACC + LEN_ACC)
#define LEN_SLOTS (256 * 16)
#define OFF_INFO (OFF_SLOTS + LEN_SLOTS)

// ---------------- init: out[:B] rows = b ----------------
__global__ void k_init_bias(float* __restrict__ out, const float* __restrict__ b) {
    const int n4 = BN * DD / 4;  // 3,200,000 float4s
    const float4* b4 = (const float4*)b;
    float4* o4 = (float4*)out;
    for (int i = blockIdx.x * blockDim.x + threadIdx.x; i < n4;
         i += gridDim.x * blockDim.x) {
        o4[i] = b4[i & 31];
    }
}

// ---------------- GEMM: h = [X_B; codebook*warm] @ W ----------------
// block 256 = 128 cols x 2 row-groups; each thread: 16 rows, 1 col.
// LDS: half of W (32KB) + 32-row X tile (16KB) = 48KB -> 3 blocks/CU.
__launch_bounds__(256)
__global__ void k_gemm(const float* __restrict__ X_B, const float* __restrict__ codebook,
                       const float* __restrict__ W, const float* __restrict__ warm,
                       float* __restrict__ h) {
    __shared__ float Wl[64 * DD];   // 32KB: 64 k-rows of W
    __shared__ float Xl[32 * DD];   // 16KB
    const int tid = threadIdx.x;
    const int col = tid & 127;
    const int rowg = tid >> 7;           // 0/1
    const int r0 = blockIdx.x * 32;
    const float wu = *warm;

    // load X tile: 1024 float4s, 4 per thread
    {
        const float4* xb4 = (const float4*)X_B;
        const float4* cb4 = (const float4*)codebook;
        float4* xl4 = (float4*)Xl;
        for (int f = tid; f < 1024; f += 256) {
            int lr = f >> 5, c4 = f & 31;
            int R = r0 + lr;
            float4 v;
            if (R < BN) {
                v = xb4[(size_t)R * 32 + c4];
            } else {
                v = cb4[(size_t)(R - BN) * 32 + c4];
                v.x *= wu; v.y *= wu; v.z *= wu; v.w *= wu;
            }
            xl4[f] = v;
        }
    }

    float acc[16];
#pragma unroll
    for (int r = 0; r < 16; r++) acc[r] = 0.f;

    const float4* W4 = (const float4*)W;
    for (int half = 0; half < 2; half++) {
        __syncthreads();  // X tile ready (half 0) / Wl free to overwrite (half 1)
        {
            float4* wl4 = (float4*)Wl;
            for (int f = tid; f < 2048; f += 256)
                wl4[f] = W4[half * 2048 + f];
        }
        __syncthreads();
#pragma unroll
        for (int k0 = 0; k0 < 64; k0 += 4) {
            float w0 = Wl[(k0 + 0) * DD + col];
            float w1 = Wl[(k0 + 1) * DD + col];
            float w2 = Wl[(k0 + 2) * DD + col];
            float w3 = Wl[(k0 + 3) * DD + col];
#pragma unroll
            for (int r = 0; r < 16; r++) {
                const float4 xv =
                    *(const float4*)&Xl[(rowg * 16 + r) * DD + half * 64 + k0];
                acc[r] += xv.x * w0 + xv.y * w1 + xv.z * w2 + xv.w * w3;
            }
        }
    }

#pragma unroll
    for (int r = 0; r < 16; r++) {
        int R = r0 + rowg * 16 + r;
        h[(size_t)R * DD + col] = acc[r];
    }
}

// ---------------- xb_norm: mean of row L2 norms of X_B ----------------
__global__ void k_xbnorm(const float* __restrict__ X_B, float* __restrict__ slots) {
    const int wave = threadIdx.x >> 6;   // 0..3
    const int lane = threadIdx.x & 63;
    const int row = blockIdx.x * 4 + wave;   // grid = 25000
    const float2 v = ((const float2*)(X_B + (size_t)row * DD))[lane];
    float s = v.x * v.x + v.y * v.y;
#pragma unroll
    for (int off = 32; off > 0; off >>= 1) s += __shfl_down(s, off);
    __shared__ float ls[4];
    if (lane == 0) ls[wave] = sqrtf(s);
    __syncthreads();
    if (threadIdx.x == 0) {
        float t = ls[0] + ls[1] + ls[2] + ls[3];
        unsafeAtomicAdd(&slots[(blockIdx.x & 255) * 16], t);
    }
}

// ---------------- scatter: both edge halves ----------------
// one wave handles 64 edges cooperatively (prefetch + shfl-broadcast),
// 64 lanes x float2 cover the 128-float h row per edge.
__global__ void k_scatter(const float* __restrict__ h,
                          const int* __restrict__ edge_dst,
                          const int* __restrict__ edge_src,
                          const float* __restrict__ ew,
                          const int* __restrict__ cidx,
                          float* __restrict__ out, float* __restrict__ accM) {
    const int lane = threadIdx.x & 63;
    const int waveId = (blockIdx.x * blockDim.x + threadIdx.x) >> 6;
    const int nWaves = (gridDim.x * blockDim.x) >> 6;
    float* acc = accM + (size_t)(blockIdx.x & (NCOPY - 1)) * NM * DD;
    const int nChunks = (EN + 63) / 64;   // 7813
    for (int ch = waveId; ch < nChunks; ch += nWaves) {
        const int e0 = ch * 64;
        const int myE = e0 + lane;
        int sv = 0, dv = 0, mv = -1;
        float wv = 0.f;
        if (myE < EN) {
            sv = edge_src[myE];
            dv = edge_dst[myE];
            wv = ew[myE];
            mv = (sv < BN) ? -1 : cidx[sv];
        }
        const int cnt = min(64, EN - e0);
        for (int i = 0; i < cnt; i++) {
            const int src = __shfl(sv, i);
            const int dst = __shfl(dv, i);
            const int m   = __shfl(mv, i);
            const float w = __shfl(wv, i);
            const int srow = (m < 0) ? src : (BN + m);
            const float2 hv = *(const float2*)(h + (size_t)srow * DD + lane * 2);
            float* op = out + (size_t)dst * DD + lane * 2;
            unsafeAtomicAdd(op,     hv.x * w);
            unsafeAtomicAdd(op + 1, hv.y * w);
            if (m >= 0) {
                const float2 hd = *(const float2*)(h + (size_t)dst * DD + lane * 2);
                float* ap = acc + (size_t)m * DD + lane * 2;
                unsafeAtomicAdd(ap,     hd.x * w);
                unsafeAtomicAdd(ap + 1, hd.y * w);
            }
        }
    }
}

// ---------------- finalize M: info = sum((sum_copies accM + b) * grad) ----------------
__global__ void k_finalize_M(const float* __restrict__ accM,
                             const float* __restrict__ grad,
                             const float* __restrict__ b,
                             float* __restrict__ info) {
    const int t = blockIdx.x * blockDim.x + threadIdx.x;  // grid 512x256 = 131072
    const int m = t >> 5, j4 = t & 31;
    float4 tot = make_float4(0.f, 0.f, 0.f, 0.f);
    for (int c = 0; c < NCOPY; c++) {
        const float4 v = *(const float4*)(accM + ((size_t)c * NM + m) * DD + j4 * 4);
        tot.x += v.x; tot.y += v.y; tot.z += v.z; tot.w += v.w;
    }
    const float4 b4 = ((const float4*)b)[j4];
    const float4 g4 = *(const float4*)(grad + (size_t)m * DD + j4 * 4);
    float c = (tot.x + b4.x) * g4.x + (tot.y + b4.y) * g4.y +
              (tot.z + b4.z) * g4.z + (tot.w + b4.w) * g4.w;
#pragma unroll
    for (int off = 32; off > 0; off >>= 1) c += __shfl_down(c, off);
    __shared__ float ls[4];
    const int lane = threadIdx.x & 63, wv = threadIdx.x >> 6;
    if (lane == 0) ls[wv] = c;
    __syncthreads();
    if (threadIdx.x == 0) unsafeAtomicAdd(info, ls[0] + ls[1] + ls[2] + ls[3]);
}

// ---------------- finalize scalars ----------------
__global__ void k_finalize_scalars(const float* __restrict__ slots,
                                   const float* __restrict__ info,
                                   const float* __restrict__ warm,
                                   float* __restrict__ out_tail) {
    float v = slots[threadIdx.x * 16];   // 256 threads, 256 slots
#pragma unroll
    for (int off = 32; off > 0; off >>= 1) v += __shfl_down(v, off);
    __shared__ float ls[4];
    if ((threadIdx.x & 63) == 0) ls[threadIdx.x >> 6] = v;
    __syncthreads();
    if (threadIdx.x == 0) {
        out_tail[0] = (ls[0] + ls[1] + ls[2] + ls[3]) / (float)BN;
        out_tail[1] = info[0] * warm[0];
    }
}

extern "C" void kernel_launch(void* const* d_in, const int* in_sizes, int n_in,
                              void* d_out, int out_size, void* d_ws, size_t ws_size,
                              hipStream_t stream) {
    const float* X_B      = (const float*)d_in[0];
    const int*   edge_dst = (const int*)d_in[1];
    const int*   edge_src = (const int*)d_in[2];
    const float* ew       = (const float*)d_in[3];
    const int*   cidx     = (const int*)d_in[5];
    const float* codebook = (const float*)d_in[6];
    const float* grad     = (const float*)d_in[7];
    const float* W        = (const float*)d_in[8];
    const float* b        = (const float*)d_in[9];
    const float* warm     = (const float*)d_in[10];
    float* out = (float*)d_out;
    float* ws  = (float*)d_ws;

    float* h     = ws;
    float* accM  = ws + OFF_ACC;
    float* slots = ws + OFF_SLOTS;
    float* info  = ws + OFF_INFO;

    // zero accM copies + slots + info
    hipMemsetAsync(accM, 0, (LEN_ACC + LEN_SLOTS + 16) * sizeof(float), stream);
    k_init_bias<<<2048, 256, 0, stream>>>(out, b);
    k_gemm<<<NROWS / 32, 256, 0, stream>>>(X_B, codebook, W, warm, h);
    k_xbnorm<<<BN / 4, 256, 0, stream>>>(X_B, slots);
    k_scatter<<<1024, 256, 0, stream>>>(h, edge_dst, edge_src, ew, cidx, out, accM);
    k_finalize_M<<<512, 256, 0, stream>>>(accM, grad, b, info);
    k_finalize_scalars<<<1, 256, 0, stream>>>(slots, info, warm, out + (size_t)BN * DD);
}

// Round 2
// 527.924 us; speedup vs baseline: 2.1246x; 2.1246x over previous
//
#include <hip/hip_runtime.h>

#define BN 100000
#define DD 128
#define EN 500000
#define NM 4096
#define NROWS (BN + NM)     // 104096

// ---- ws layout (4-byte units) ----
#define OFF_H      0
#define LEN_H      ((size_t)NROWS * DD)           // 13,324,288
#define OFF_CNT    (LEN_H)                        // 100000 ints  (memset 0)
#define OFF_SLOTS  (OFF_CNT + BN)                 // 256 f xbnorm (memset 0)
#define OFF_ISLOTS (OFF_SLOTS + 256)              // 256 f info   (memset 0)
#define OFF_RS     (OFF_ISLOTS + 256)             // 100001 ints
#define OFF_NEXT   (OFF_RS + BN + 1)              // 100000 ints
#define OFF_SRC    (OFF_NEXT + BN)                // 500000 ints
#define OFF_WQ     (OFF_SRC + EN)                 // 500000 f
#define OFF_BS     (OFF_WQ + EN)                  // 128 ints

// ---------------- GEMM: h = [X_B; codebook*warm] @ W ----------------
__launch_bounds__(256)
__global__ void k_gemm(const float* __restrict__ X_B, const float* __restrict__ codebook,
                       const float* __restrict__ W, const float* __restrict__ warm,
                       float* __restrict__ h) {
    __shared__ float Wl[64 * DD];
    __shared__ float Xl[32 * DD];
    const int tid = threadIdx.x;
    const int col = tid & 127;
    const int rowg = tid >> 7;
    const int r0 = blockIdx.x * 32;
    const float wu = *warm;
    {
        const float4* xb4 = (const float4*)X_B;
        const float4* cb4 = (const float4*)codebook;
        float4* xl4 = (float4*)Xl;
        for (int f = tid; f < 1024; f += 256) {
            int lr = f >> 5, c4 = f & 31;
            int R = r0 + lr;
            float4 v;
            if (R < BN) {
                v = xb4[(size_t)R * 32 + c4];
            } else {
                v = cb4[(size_t)(R - BN) * 32 + c4];
                v.x *= wu; v.y *= wu; v.z *= wu; v.w *= wu;
            }
            xl4[f] = v;
        }
    }
    float acc[16];
#pragma unroll
    for (int r = 0; r < 16; r++) acc[r] = 0.f;
    const float4* W4 = (const float4*)W;
    for (int half = 0; half < 2; half++) {
        __syncthreads();
        {
            float4* wl4 = (float4*)Wl;
            for (int f = tid; f < 2048; f += 256)
                wl4[f] = W4[half * 2048 + f];
        }
        __syncthreads();
#pragma unroll
        for (int k0 = 0; k0 < 64; k0 += 4) {
            float w0 = Wl[(k0 + 0) * DD + col];
            float w1 = Wl[(k0 + 1) * DD + col];
            float w2 = Wl[(k0 + 2) * DD + col];
            float w3 = Wl[(k0 + 3) * DD + col];
#pragma unroll
            for (int r = 0; r < 16; r++) {
                const float4 xv =
                    *(const float4*)&Xl[(rowg * 16 + r) * DD + half * 64 + k0];
                acc[r] += xv.x * w0 + xv.y * w1 + xv.z * w2 + xv.w * w3;
            }
        }
    }
#pragma unroll
    for (int r = 0; r < 16; r++) {
        int R = r0 + rowg * 16 + r;
        h[(size_t)R * DD + col] = acc[r];
    }
}

// ---------------- histogram by dst ----------------
__global__ void k_hist(const int* __restrict__ edge_dst, int* __restrict__ cnt) {
    for (int e = blockIdx.x * blockDim.x + threadIdx.x; e < EN;
         e += gridDim.x * blockDim.x)
        atomicAdd(&cnt[edge_dst[e]], 1);
}

// ---------------- scan phase 1: per-block exclusive scan of cnt ----------------
__launch_bounds__(1024)
__global__ void k_scan1(const int* __restrict__ cnt, int* __restrict__ rs,
                        int* __restrict__ bs) {
    __shared__ int sd[1024];
    const int t = threadIdx.x;
    const int i = blockIdx.x * 1024 + t;
    int v = (i < BN) ? cnt[i] : 0;
    sd[t] = v;
    __syncthreads();
    for (int off = 1; off < 1024; off <<= 1) {
        int x = (t >= off) ? sd[t - off] : 0;
        __syncthreads();
        sd[t] += x;
        __syncthreads();
    }
    if (i < BN) rs[i] = sd[t] - v;       // exclusive within block
    if (t == 0) bs[blockIdx.x] = sd[1023];
}

// ---------------- scan phase 2: scan the 98 block sums ----------------
__global__ void k_scan2(int* __restrict__ bs) {
    __shared__ int sd[128];
    const int t = threadIdx.x;
    int v = (t < 98) ? bs[t] : 0;
    sd[t] = v;
    __syncthreads();
    for (int off = 1; off < 128; off <<= 1) {
        int x = (t >= off) ? sd[t - off] : 0;
        __syncthreads();
        sd[t] += x;
        __syncthreads();
    }
    bs[t] = sd[t] - v;                   // exclusive
}

// ---------------- scan phase 3: add block offsets; init next ----------------
__launch_bounds__(1024)
__global__ void k_scan3(int* __restrict__ rs, int* __restrict__ next,
                        const int* __restrict__ bs) {
    const int i = blockIdx.x * 1024 + threadIdx.x;
    if (i < BN) {
        int v = rs[i] + bs[blockIdx.x];
        rs[i] = v;
        next[i] = v;
    }
    if (i == 0) rs[BN] = EN;
}

// ---------------- slot-scatter edges into CSR order ----------------
__global__ void k_slot(const int* __restrict__ edge_dst, const int* __restrict__ edge_src,
                       const float* __restrict__ ew, const int* __restrict__ cidx,
                       int* __restrict__ next, int* __restrict__ srcq,
                       float* __restrict__ wq) {
    for (int e = blockIdx.x * blockDim.x + threadIdx.x; e < EN;
         e += gridDim.x * blockDim.x) {
        const int d = edge_dst[e];
        const int s = edge_src[e];
        const int p = atomicAdd(&next[d], 1);
        srcq[p] = (s < BN) ? s : (BN + cidx[s]);
        wq[p] = ew[e];
    }
}

// ---------------- aggregate: one wave per output row, no atomics ----------------
__launch_bounds__(256)
__global__ void k_aggregate(const float* __restrict__ h, const int* __restrict__ rs,
                            const int* __restrict__ srcq, const float* __restrict__ wq,
                            const float* __restrict__ b, float* __restrict__ out) {
    const int lane = threadIdx.x & 63;
    const int row = blockIdx.x * 4 + (threadIdx.x >> 6);   // grid 25000
    const int s0 = rs[row], s1 = rs[row + 1];
    const float2* b2 = (const float2*)b;
    float2 acc = b2[lane];
    const float2* h2 = (const float2*)h;
    for (int i = s0; i < s1; i++) {
        const int sr = srcq[i];
        const float w = wq[i];
        const float2 hv = h2[(size_t)sr * 64 + lane];
        acc.x += hv.x * w;
        acc.y += hv.y * w;
    }
    ((float2*)out)[(size_t)row * 64 + lane] = acc;
}

// ---------------- info: edge dots + b.grad term ----------------
__launch_bounds__(256)
__global__ void k_info(const float* __restrict__ h, const int* __restrict__ edge_dst,
                       const int* __restrict__ edge_src, const float* __restrict__ ew,
                       const int* __restrict__ cidx, const float* __restrict__ grad,
                       const float* __restrict__ b, float* __restrict__ islots) {
    const int lane = threadIdx.x & 63;
    const int gtid = blockIdx.x * blockDim.x + threadIdx.x;  // 2048*256 = 524288 = NM*DD
    const int wid = gtid >> 6;                                // 8192 waves
    float p = b[gtid & 127] * grad[gtid];                     // bias.grad term, one elem/thread
    const float2* h2 = (const float2*)h;
    const float2* g2 = (const float2*)grad;
    for (int e = wid; e < EN; e += 8192) {
        const int s = edge_src[e];
        if (s < BN) continue;
        const int d = edge_dst[e];
        const float w = ew[e];
        const int m = cidx[s];
        const float2 hv = h2[(size_t)d * 64 + lane];
        const float2 gv = g2[(size_t)m * 64 + lane];
        p += w * (hv.x * gv.x + hv.y * gv.y);
    }
#pragma unroll
    for (int off = 32; off > 0; off >>= 1) p += __shfl_down(p, off);
    if (lane == 0) unsafeAtomicAdd(&islots[blockIdx.x & 255], p);
}

// ---------------- xb_norm ----------------
__global__ void k_xbnorm(const float* __restrict__ X_B, float* __restrict__ slots) {
    const int wave = threadIdx.x >> 6;
    const int lane = threadIdx.x & 63;
    const int row = blockIdx.x * 4 + wave;   // grid 25000
    const float2 v = ((const float2*)(X_B + (size_t)row * DD))[lane];
    float s = v.x * v.x + v.y * v.y;
#pragma unroll
    for (int off = 32; off > 0; off >>= 1) s += __shfl_down(s, off);
    __shared__ float ls[4];
    if (lane == 0) ls[wave] = sqrtf(s);
    __syncthreads();
    if (threadIdx.x == 0)
        unsafeAtomicAdd(&slots[blockIdx.x & 255], ls[0] + ls[1] + ls[2] + ls[3]);
}

// ---------------- finalize scalars ----------------
__global__ void k_finalize(const float* __restrict__ slots, const float* __restrict__ islots,
                           const float* __restrict__ warm, float* __restrict__ out_tail) {
    float v = slots[threadIdx.x];
    float u = islots[threadIdx.x];
#pragma unroll
    for (int off = 32; off > 0; off >>= 1) {
        v += __shfl_down(v, off);
        u += __shfl_down(u, off);
    }
    __shared__ float lv[4], lu[4];
    if ((threadIdx.x & 63) == 0) { lv[threadIdx.x >> 6] = v; lu[threadIdx.x >> 6] = u; }
    __syncthreads();
    if (threadIdx.x == 0) {
        out_tail[0] = (lv[0] + lv[1] + lv[2] + lv[3]) / (float)BN;
        out_tail[1] = (lu[0] + lu[1] + lu[2] + lu[3]) * warm[0];
    }
}

extern "C" void kernel_launch(void* const* d_in, const int* in_sizes, int n_in,
                              void* d_out, int out_size, void* d_ws, size_t ws_size,
                              hipStream_t stream) {
    const float* X_B      = (const float*)d_in[0];
    const int*   edge_dst = (const int*)d_in[1];
    const int*   edge_src = (const int*)d_in[2];
    const float* ew       = (const float*)d_in[3];
    const int*   cidx     = (const int*)d_in[5];
    const float* codebook = (const float*)d_in[6];
    const float* grad     = (const float*)d_in[7];
    const float* W        = (const float*)d_in[8];
    const float* b        = (const float*)d_in[9];
    const float* warm     = (const float*)d_in[10];
    float* out = (float*)d_out;
    float* ws  = (float*)d_ws;

    float* h      = ws + OFF_H;
    int*   cnt    = (int*)(ws + OFF_CNT);
    float* slots  = ws + OFF_SLOTS;
    float* islots = ws + OFF_ISLOTS;
    int*   rs     = (int*)(ws + OFF_RS);
    int*   next   = (int*)(ws + OFF_NEXT);
    int*   srcq   = (int*)(ws + OFF_SRC);
    float* wq     = ws + OFF_WQ;
    int*   bs     = (int*)(ws + OFF_BS);

    // zero cnt + slots + islots (contiguous)
    hipMemsetAsync(cnt, 0, (BN + 512) * sizeof(float), stream);

    k_gemm<<<NROWS / 32, 256, 0, stream>>>(X_B, codebook, W, warm, h);
    k_hist<<<512, 256, 0, stream>>>(edge_dst, cnt);
    k_scan1<<<98, 1024, 0, stream>>>(cnt, rs, bs);
    k_scan2<<<1, 128, 0, stream>>>(bs);
    k_scan3<<<98, 1024, 0, stream>>>(rs, next, bs);
    k_slot<<<512, 256, 0, stream>>>(edge_dst, edge_src, ew, cidx, next, srcq, wq);
    k_xbnorm<<<BN / 4, 256, 0, stream>>>(X_B, slots);
    k_aggregate<<<BN / 4, 256, 0, stream>>>(h, rs, srcq, wq, b, out);
    k_info<<<2048, 256, 0, stream>>>(h, edge_dst, edge_src, ew, cidx, grad, b, islots);
    k_finalize<<<1, 256, 0, stream>>>(slots, islots, warm, out + (size_t)BN * DD);
}

// Round 3
// 400.991 us; speedup vs baseline: 2.7971x; 1.3165x over previous
//
#include <hip/hip_runtime.h>

#define BN 100000
#define DD 128
#define EN 500000
#define NM 4096
#define NROWS (BN + NM)     // 104096
#define MT 128              // gemm row tile

// ---- ws layout (4-byte units) ----
#define OFF_H      0
#define LEN_H      ((size_t)NROWS * DD)           // 13,324,288
#define OFF_CNT    (LEN_H)                        // 100000 ints  (memset 0)
#define OFF_SLOTS  (OFF_CNT + BN)                 // 256 f xbnorm (memset 0)
#define OFF_ISLOTS (OFF_SLOTS + 256)              // 256 f info   (memset 0)
#define OFF_RS     (OFF_ISLOTS + 256)             // 100001 ints
#define OFF_NEXT   (OFF_RS + BN + 1)              // 100000 ints
#define OFF_SRC    (OFF_NEXT + BN)                // 500000 ints
#define OFF_WQ     (OFF_SRC + EN)                 // 500000 f
#define OFF_BS     (OFF_WQ + EN)                  // 128 ints

// ---------------- GEMM: h = [X_B; codebook*warm] @ W ----------------
// 128x128 tile / block, 256 thr, 8x8 per thread (split 4+4 at offset 64 for
// conflict-free ds_read_b128), X staged transposed in LDS, K chunks of 32.
__launch_bounds__(256)
__global__ void k_gemm(const float* __restrict__ X_B, const float* __restrict__ codebook,
                       const float* __restrict__ W, const float* __restrict__ warm,
                       float* __restrict__ h) {
    __shared__ __align__(16) float XlT[32 * 128];   // [k][r] 16KB
    __shared__ __align__(16) float Wl[32 * 128];    // [k][c] 16KB
    const int tid = threadIdx.x;
    const int tx = tid & 15, ty = tid >> 4;
    const int r0 = blockIdx.x * MT;
    const float wu = *warm;

    float acc[8][8];
#pragma unroll
    for (int i = 0; i < 8; i++)
#pragma unroll
        for (int j = 0; j < 8; j++) acc[i][j] = 0.f;

    const float4* xb4 = (const float4*)X_B;
    const float4* cb4 = (const float4*)codebook;
    const float4* W4 = (const float4*)W;

    for (int kc = 0; kc < 4; kc++) {
        __syncthreads();   // previous chunk's reads done
        // stage X chunk transposed: 1024 float4 loads -> 4096 scalar stores
#pragma unroll
        for (int i = 0; i < 4; i++) {
            const int f = i * 256 + tid;
            const int r = f >> 3, kq = f & 7;
            const int R = r0 + r;
            float4 v = make_float4(0.f, 0.f, 0.f, 0.f);
            if (R < NROWS) {
                if (R < BN) {
                    v = xb4[(size_t)R * 32 + kc * 8 + kq];
                } else {
                    v = cb4[(size_t)(R - BN) * 32 + kc * 8 + kq];
                    v.x *= wu; v.y *= wu; v.z *= wu; v.w *= wu;
                }
            }
            XlT[(kq * 4 + 0) * 128 + r] = v.x;
            XlT[(kq * 4 + 1) * 128 + r] = v.y;
            XlT[(kq * 4 + 2) * 128 + r] = v.z;
            XlT[(kq * 4 + 3) * 128 + r] = v.w;
        }
        // stage W chunk: direct float4 copy
#pragma unroll
        for (int i = 0; i < 4; i++) {
            const int f = i * 256 + tid;
            ((float4*)Wl)[f] = W4[kc * 1024 + f];
        }
        __syncthreads();
#pragma unroll 4
        for (int k = 0; k < 32; k++) {
            const float4 a0 = *(const float4*)&XlT[k * 128 + ty * 4];
            const float4 a1 = *(const float4*)&XlT[k * 128 + 64 + ty * 4];
            const float4 b0 = *(const float4*)&Wl[k * 128 + tx * 4];
            const float4 b1 = *(const float4*)&Wl[k * 128 + 64 + tx * 4];
            const float ar[8] = {a0.x, a0.y, a0.z, a0.w, a1.x, a1.y, a1.z, a1.w};
            const float bc[8] = {b0.x, b0.y, b0.z, b0.w, b1.x, b1.y, b1.z, b1.w};
#pragma unroll
            for (int i = 0; i < 8; i++)
#pragma unroll
                for (int j = 0; j < 8; j++) acc[i][j] += ar[i] * bc[j];
        }
    }

    // epilogue: 8 rows x 2 float4 stores
#pragma unroll
    for (int i = 0; i < 8; i++) {
        const int R = r0 + ((i < 4) ? (ty * 4 + i) : (64 + ty * 4 + i - 4));
        if (R < NROWS) {
            float4 o0 = make_float4(acc[i][0], acc[i][1], acc[i][2], acc[i][3]);
            float4 o1 = make_float4(acc[i][4], acc[i][5], acc[i][6], acc[i][7]);
            *(float4*)&h[(size_t)R * DD + tx * 4] = o0;
            *(float4*)&h[(size_t)R * DD + 64 + tx * 4] = o1;
        }
    }
}

// ---------------- histogram by dst ----------------
__global__ void k_hist(const int* __restrict__ edge_dst, int* __restrict__ cnt) {
    for (int e = blockIdx.x * blockDim.x + threadIdx.x; e < EN;
         e += gridDim.x * blockDim.x)
        atomicAdd(&cnt[edge_dst[e]], 1);
}

// ---------------- scan phase 1 ----------------
__launch_bounds__(1024)
__global__ void k_scan1(const int* __restrict__ cnt, int* __restrict__ rs,
                        int* __restrict__ bs) {
    __shared__ int sd[1024];
    const int t = threadIdx.x;
    const int i = blockIdx.x * 1024 + t;
    int v = (i < BN) ? cnt[i] : 0;
    sd[t] = v;
    __syncthreads();
    for (int off = 1; off < 1024; off <<= 1) {
        int x = (t >= off) ? sd[t - off] : 0;
        __syncthreads();
        sd[t] += x;
        __syncthreads();
    }
    if (i < BN) rs[i] = sd[t] - v;
    if (t == 0) bs[blockIdx.x] = sd[1023];
}

// ---------------- scan phase 2 ----------------
__global__ void k_scan2(int* __restrict__ bs) {
    __shared__ int sd[128];
    const int t = threadIdx.x;
    int v = (t < 98) ? bs[t] : 0;
    sd[t] = v;
    __syncthreads();
    for (int off = 1; off < 128; off <<= 1) {
        int x = (t >= off) ? sd[t - off] : 0;
        __syncthreads();
        sd[t] += x;
        __syncthreads();
    }
    bs[t] = sd[t] - v;
}

// ---------------- scan phase 3 ----------------
__launch_bounds__(1024)
__global__ void k_scan3(int* __restrict__ rs, int* __restrict__ next,
                        const int* __restrict__ bs) {
    const int i = blockIdx.x * 1024 + threadIdx.x;
    if (i < BN) {
        int v = rs[i] + bs[blockIdx.x];
        rs[i] = v;
        next[i] = v;
    }
    if (i == 0) rs[BN] = EN;
}

// ---------------- slot-scatter edges into CSR order ----------------
__global__ void k_slot(const int* __restrict__ edge_dst, const int* __restrict__ edge_src,
                       const float* __restrict__ ew, const int* __restrict__ cidx,
                       int* __restrict__ next, int* __restrict__ srcq,
                       float* __restrict__ wq) {
    for (int e = blockIdx.x * blockDim.x + threadIdx.x; e < EN;
         e += gridDim.x * blockDim.x) {
        const int d = edge_dst[e];
        const int s = edge_src[e];
        const int p = atomicAdd(&next[d], 1);
        srcq[p] = (s < BN) ? s : (BN + cidx[s]);
        wq[p] = ew[e];
    }
}

// ---------------- aggregate: one wave per output row, no atomics ----------------
__launch_bounds__(256)
__global__ void k_aggregate(const float* __restrict__ h, const int* __restrict__ rs,
                            const int* __restrict__ srcq, const float* __restrict__ wq,
                            const float* __restrict__ b, float* __restrict__ out) {
    const int lane = threadIdx.x & 63;
    const int row = blockIdx.x * 4 + (threadIdx.x >> 6);   // grid 25000
    const int s0 = rs[row], s1 = rs[row + 1];
    const float2* b2 = (const float2*)b;
    float2 acc = b2[lane];
    const float2* h2 = (const float2*)h;
    for (int i = s0; i < s1; i++) {
        const int sr = srcq[i];
        const float w = wq[i];
        const float2 hv = h2[(size_t)sr * 64 + lane];
        acc.x += hv.x * w;
        acc.y += hv.y * w;
    }
    ((float2*)out)[(size_t)row * 64 + lane] = acc;
}

// ---------------- info: edge dots + b.grad term ----------------
__launch_bounds__(256)
__global__ void k_info(const float* __restrict__ h, const int* __restrict__ edge_dst,
                       const int* __restrict__ edge_src, const float* __restrict__ ew,
                       const int* __restrict__ cidx, const float* __restrict__ grad,
                       const float* __restrict__ b, float* __restrict__ islots) {
    const int lane = threadIdx.x & 63;
    const int gtid = blockIdx.x * blockDim.x + threadIdx.x;  // 2048*256 = NM*DD
    const int wid = gtid >> 6;                                // 8192 waves
    float p = b[gtid & 127] * grad[gtid];                     // bias.grad term
    const float2* h2 = (const float2*)h;
    const float2* g2 = (const float2*)grad;
    for (int e = wid; e < EN; e += 8192) {
        const int s = edge_src[e];
        if (s < BN) continue;
        const int d = edge_dst[e];
        const float w = ew[e];
        const int m = cidx[s];
        const float2 hv = h2[(size_t)d * 64 + lane];
        const float2 gv = g2[(size_t)m * 64 + lane];
        p += w * (hv.x * gv.x + hv.y * gv.y);
    }
#pragma unroll
    for (int off = 32; off > 0; off >>= 1) p += __shfl_down(p, off);
    if (lane == 0) unsafeAtomicAdd(&islots[blockIdx.x & 255], p);
}

// ---------------- xb_norm ----------------
__global__ void k_xbnorm(const float* __restrict__ X_B, float* __restrict__ slots) {
    const int wave = threadIdx.x >> 6;
    const int lane = threadIdx.x & 63;
    const int row = blockIdx.x * 4 + wave;   // grid 25000
    const float2 v = ((const float2*)(X_B + (size_t)row * DD))[lane];
    float s = v.x * v.x + v.y * v.y;
#pragma unroll
    for (int off = 32; off > 0; off >>= 1) s += __shfl_down(s, off);
    __shared__ float ls[4];
    if (lane == 0) ls[wave] = sqrtf(s);
    __syncthreads();
    if (threadIdx.x == 0)
        unsafeAtomicAdd(&slots[blockIdx.x & 255], ls[0] + ls[1] + ls[2] + ls[3]);
}

// ---------------- finalize scalars ----------------
__global__ void k_finalize(const float* __restrict__ slots, const float* __restrict__ islots,
                           const float* __restrict__ warm, float* __restrict__ out_tail) {
    float v = slots[threadIdx.x];
    float u = islots[threadIdx.x];
#pragma unroll
    for (int off = 32; off > 0; off >>= 1) {
        v += __shfl_down(v, off);
        u += __shfl_down(u, off);
    }
    __shared__ float lv[4], lu[4];
    if ((threadIdx.x & 63) == 0) { lv[threadIdx.x >> 6] = v; lu[threadIdx.x >> 6] = u; }
    __syncthreads();
    if (threadIdx.x == 0) {
        out_tail[0] = (lv[0] + lv[1] + lv[2] + lv[3]) / (float)BN;
        out_tail[1] = (lu[0] + lu[1] + lu[2] + lu[3]) * warm[0];
    }
}

extern "C" void kernel_launch(void* const* d_in, const int* in_sizes, int n_in,
                              void* d_out, int out_size, void* d_ws, size_t ws_size,
                              hipStream_t stream) {
    const float* X_B      = (const float*)d_in[0];
    const int*   edge_dst = (const int*)d_in[1];
    const int*   edge_src = (const int*)d_in[2];
    const float* ew       = (const float*)d_in[3];
    const int*   cidx     = (const int*)d_in[5];
    const float* codebook = (const float*)d_in[6];
    const float* grad     = (const float*)d_in[7];
    const float* W        = (const float*)d_in[8];
    const float* b        = (const float*)d_in[9];
    const float* warm     = (const float*)d_in[10];
    float* out = (float*)d_out;
    float* ws  = (float*)d_ws;

    float* h      = ws + OFF_H;
    int*   cnt    = (int*)(ws + OFF_CNT);
    float* slots  = ws + OFF_SLOTS;
    float* islots = ws + OFF_ISLOTS;
    int*   rs     = (int*)(ws + OFF_RS);
    int*   next   = (int*)(ws + OFF_NEXT);
    int*   srcq   = (int*)(ws + OFF_SRC);
    float* wq     = ws + OFF_WQ;
    int*   bs     = (int*)(ws + OFF_BS);

    hipMemsetAsync(cnt, 0, (BN + 512) * sizeof(float), stream);

    k_gemm<<<(NROWS + MT - 1) / MT, 256, 0, stream>>>(X_B, codebook, W, warm, h);
    k_hist<<<512, 256, 0, stream>>>(edge_dst, cnt);
    k_scan1<<<98, 1024, 0, stream>>>(cnt, rs, bs);
    k_scan2<<<1, 128, 0, stream>>>(bs);
    k_scan3<<<98, 1024, 0, stream>>>(rs, next, bs);
    k_slot<<<512, 256, 0, stream>>>(edge_dst, edge_src, ew, cidx, next, srcq, wq);
    k_xbnorm<<<BN / 4, 256, 0, stream>>>(X_B, slots);
    k_aggregate<<<BN / 4, 256, 0, stream>>>(h, rs, srcq, wq, b, out);
    k_info<<<2048, 256, 0, stream>>>(h, edge_dst, edge_src, ew, cidx, grad, b, islots);
    k_finalize<<<1, 256, 0, stream>>>(slots, islots, warm, out + (size_t)BN * DD);
}

// Round 4
// 326.519 us; speedup vs baseline: 3.4351x; 1.2281x over previous
//
#include <hip/hip_runtime.h>

#define BN 100000
#define DD 128
#define EN 500000
#define NM 4096
#define NROWS (BN + NM)     // 104096
#define MT 128              // gemm row tile

// ---- ws layout (4-byte units) ----
#define OFF_H      0
#define LEN_H      ((size_t)NROWS * DD)           // 13,324,288
#define OFF_CNT    (LEN_H)                        // 100000 ints  (memset 0)
#define OFF_SLOTS  (OFF_CNT + BN)                 // 256 f xbnorm (memset 0)
#define OFF_ISLOTS (OFF_SLOTS + 256)              // 256 f info   (memset 0)
#define OFF_RS     (OFF_ISLOTS + 256)             // 100001 ints
#define OFF_NEXT   (OFF_RS + BN + 1)              // 100000 ints
#define OFF_SRC    (OFF_NEXT + BN)                // 500000 ints
#define OFF_WQ     (OFF_SRC + EN)                 // 500000 f
#define OFF_BS     (OFF_WQ + EN)                  // 128 ints

// ---------------- GEMM: h = [X_B; codebook*warm] @ W ----------------
__launch_bounds__(256)
__global__ void k_gemm(const float* __restrict__ X_B, const float* __restrict__ codebook,
                       const float* __restrict__ W, const float* __restrict__ warm,
                       float* __restrict__ h) {
    __shared__ __align__(16) float XlT[32 * 128];   // [k][r]
    __shared__ __align__(16) float Wl[32 * 128];    // [k][c]
    const int tid = threadIdx.x;
    const int tx = tid & 15, ty = tid >> 4;
    const int r0 = blockIdx.x * MT;
    const float wu = *warm;

    float acc[8][8];
#pragma unroll
    for (int i = 0; i < 8; i++)
#pragma unroll
        for (int j = 0; j < 8; j++) acc[i][j] = 0.f;

    const float4* xb4 = (const float4*)X_B;
    const float4* cb4 = (const float4*)codebook;
    const float4* W4 = (const float4*)W;

    for (int kc = 0; kc < 4; kc++) {
        __syncthreads();
#pragma unroll
        for (int i = 0; i < 4; i++) {
            const int f = i * 256 + tid;
            const int r = f >> 3, kq = f & 7;
            const int R = r0 + r;
            float4 v = make_float4(0.f, 0.f, 0.f, 0.f);
            if (R < NROWS) {
                if (R < BN) {
                    v = xb4[(size_t)R * 32 + kc * 8 + kq];
                } else {
                    v = cb4[(size_t)(R - BN) * 32 + kc * 8 + kq];
                    v.x *= wu; v.y *= wu; v.z *= wu; v.w *= wu;
                }
            }
            XlT[(kq * 4 + 0) * 128 + r] = v.x;
            XlT[(kq * 4 + 1) * 128 + r] = v.y;
            XlT[(kq * 4 + 2) * 128 + r] = v.z;
            XlT[(kq * 4 + 3) * 128 + r] = v.w;
        }
#pragma unroll
        for (int i = 0; i < 4; i++) {
            const int f = i * 256 + tid;
            ((float4*)Wl)[f] = W4[kc * 1024 + f];
        }
        __syncthreads();
#pragma unroll 4
        for (int k = 0; k < 32; k++) {
            const float4 a0 = *(const float4*)&XlT[k * 128 + ty * 4];
            const float4 a1 = *(const float4*)&XlT[k * 128 + 64 + ty * 4];
            const float4 b0 = *(const float4*)&Wl[k * 128 + tx * 4];
            const float4 b1 = *(const float4*)&Wl[k * 128 + 64 + tx * 4];
            const float ar[8] = {a0.x, a0.y, a0.z, a0.w, a1.x, a1.y, a1.z, a1.w};
            const float bc[8] = {b0.x, b0.y, b0.z, b0.w, b1.x, b1.y, b1.z, b1.w};
#pragma unroll
            for (int i = 0; i < 8; i++)
#pragma unroll
                for (int j = 0; j < 8; j++) acc[i][j] += ar[i] * bc[j];
        }
    }
#pragma unroll
    for (int i = 0; i < 8; i++) {
        const int R = r0 + ((i < 4) ? (ty * 4 + i) : (64 + ty * 4 + i - 4));
        if (R < NROWS) {
            float4 o0 = make_float4(acc[i][0], acc[i][1], acc[i][2], acc[i][3]);
            float4 o1 = make_float4(acc[i][4], acc[i][5], acc[i][6], acc[i][7]);
            *(float4*)&h[(size_t)R * DD + tx * 4] = o0;
            *(float4*)&h[(size_t)R * DD + 64 + tx * 4] = o1;
        }
    }
}

// ---------------- histogram by dst ----------------
__global__ void k_hist(const int* __restrict__ edge_dst, int* __restrict__ cnt) {
    for (int e = blockIdx.x * blockDim.x + threadIdx.x; e < EN;
         e += gridDim.x * blockDim.x)
        atomicAdd(&cnt[edge_dst[e]], 1);
}

// ---------------- scan phase 1 ----------------
__launch_bounds__(1024)
__global__ void k_scan1(const int* __restrict__ cnt, int* __restrict__ rs,
                        int* __restrict__ bs) {
    __shared__ int sd[1024];
    const int t = threadIdx.x;
    const int i = blockIdx.x * 1024 + t;
    int v = (i < BN) ? cnt[i] : 0;
    sd[t] = v;
    __syncthreads();
    for (int off = 1; off < 1024; off <<= 1) {
        int x = (t >= off) ? sd[t - off] : 0;
        __syncthreads();
        sd[t] += x;
        __syncthreads();
    }
    if (i < BN) rs[i] = sd[t] - v;
    if (t == 0) bs[blockIdx.x] = sd[1023];
}

// ---------------- scan phase 2 ----------------
__global__ void k_scan2(int* __restrict__ bs) {
    __shared__ int sd[128];
    const int t = threadIdx.x;
    int v = (t < 98) ? bs[t] : 0;
    sd[t] = v;
    __syncthreads();
    for (int off = 1; off < 128; off <<= 1) {
        int x = (t >= off) ? sd[t - off] : 0;
        __syncthreads();
        sd[t] += x;
        __syncthreads();
    }
    bs[t] = sd[t] - v;
}

// ---------------- scan phase 3 ----------------
__launch_bounds__(1024)
__global__ void k_scan3(int* __restrict__ rs, int* __restrict__ next,
                        const int* __restrict__ bs) {
    const int i = blockIdx.x * 1024 + threadIdx.x;
    if (i < BN) {
        int v = rs[i] + bs[blockIdx.x];
        rs[i] = v;
        next[i] = v;
    }
    if (i == 0) rs[BN] = EN;
}

// ---------------- slot-scatter edges into CSR order ----------------
__global__ void k_slot(const int* __restrict__ edge_dst, const int* __restrict__ edge_src,
                       const float* __restrict__ ew, const int* __restrict__ cidx,
                       int* __restrict__ next, int* __restrict__ srcq,
                       float* __restrict__ wq) {
    for (int e = blockIdx.x * blockDim.x + threadIdx.x; e < EN;
         e += gridDim.x * blockDim.x) {
        const int d = edge_dst[e];
        const int s = edge_src[e];
        const int p = atomicAdd(&next[d], 1);
        srcq[p] = (s < BN) ? s : (BN + cidx[s]);
        wq[p] = ew[e];
    }
}

// ---------------- fused aggregate + info + xbnorm ----------------
// one wave per output row. out[d] = b + sum(w*h[src_eff]); per-row
// gacc = sum_{m-edges} w*grad[m] (hot 2MB, L2) then info += <h[d],gacc>
// (sequential); xb_norm from X_B[d]; bias.grad term spread over first
// 2048 blocks.
__launch_bounds__(256)
__global__ void k_aggregate(const float* __restrict__ h, const int* __restrict__ rs,
                            const int* __restrict__ srcq, const float* __restrict__ wq,
                            const float* __restrict__ b, const float* __restrict__ grad,
                            const float* __restrict__ X_B, float* __restrict__ out,
                            float* __restrict__ slots, float* __restrict__ islots) {
    const int lane = threadIdx.x & 63;
    const int wave = threadIdx.x >> 6;
    const int row = blockIdx.x * 4 + wave;   // grid 25000 -> rows 0..99999
    const float2* h2 = (const float2*)h;
    const float2* g2 = (const float2*)grad;

    // bias.grad term: one grad element per thread for first 2048 blocks
    float myinfo = 0.f;
    {
        const int gid = blockIdx.x * 256 + threadIdx.x;
        if (gid < NM * DD) myinfo = b[gid & 127] * grad[gid];
    }

    // xb_norm contribution for this row
    const float2 xv = ((const float2*)X_B)[(size_t)row * 64 + lane];
    float s = xv.x * xv.x + xv.y * xv.y;
#pragma unroll
    for (int off = 32; off > 0; off >>= 1) s += __shfl_down(s, off);
    const float mynorm = (lane == 0) ? sqrtf(s) : 0.f;

    const int s0 = rs[row], s1 = rs[row + 1];
    float2 acc = ((const float2*)b)[lane];
    float2 gacc = make_float2(0.f, 0.f);
    bool anyM = false;
    for (int i = s0; i < s1; i++) {
        const int sr = srcq[i];
        const float w = wq[i];
        const float2 hv = h2[(size_t)sr * 64 + lane];
        acc.x += hv.x * w;
        acc.y += hv.y * w;
        if (sr >= BN) {   // wave-uniform branch
            const float2 gv = g2[(size_t)(sr - BN) * 64 + lane];
            gacc.x += gv.x * w;
            gacc.y += gv.y * w;
            anyM = true;
        }
    }
    ((float2*)out)[(size_t)row * 64 + lane] = acc;
    if (anyM) {
        const float2 hd = h2[(size_t)row * 64 + lane];
        myinfo += hd.x * gacc.x + hd.y * gacc.y;
    }
#pragma unroll
    for (int off = 32; off > 0; off >>= 1) myinfo += __shfl_down(myinfo, off);
    __shared__ float li[4], ln[4];
    if (lane == 0) { li[wave] = myinfo; ln[wave] = mynorm; }
    __syncthreads();
    if (threadIdx.x == 0) {
        unsafeAtomicAdd(&islots[blockIdx.x & 255], li[0] + li[1] + li[2] + li[3]);
        unsafeAtomicAdd(&slots[blockIdx.x & 255], ln[0] + ln[1] + ln[2] + ln[3]);
    }
}

// ---------------- finalize scalars ----------------
__global__ void k_finalize(const float* __restrict__ slots, const float* __restrict__ islots,
                           const float* __restrict__ warm, float* __restrict__ out_tail) {
    float v = slots[threadIdx.x];
    float u = islots[threadIdx.x];
#pragma unroll
    for (int off = 32; off > 0; off >>= 1) {
        v += __shfl_down(v, off);
        u += __shfl_down(u, off);
    }
    __shared__ float lv[4], lu[4];
    if ((threadIdx.x & 63) == 0) { lv[threadIdx.x >> 6] = v; lu[threadIdx.x >> 6] = u; }
    __syncthreads();
    if (threadIdx.x == 0) {
        out_tail[0] = (lv[0] + lv[1] + lv[2] + lv[3]) / (float)BN;
        out_tail[1] = (lu[0] + lu[1] + lu[2] + lu[3]) * warm[0];
    }
}

extern "C" void kernel_launch(void* const* d_in, const int* in_sizes, int n_in,
                              void* d_out, int out_size, void* d_ws, size_t ws_size,
                              hipStream_t stream) {
    const float* X_B      = (const float*)d_in[0];
    const int*   edge_dst = (const int*)d_in[1];
    const int*   edge_src = (const int*)d_in[2];
    const float* ew       = (const float*)d_in[3];
    const int*   cidx     = (const int*)d_in[5];
    const float* codebook = (const float*)d_in[6];
    const float* grad     = (const float*)d_in[7];
    const float* W        = (const float*)d_in[8];
    const float* b        = (const float*)d_in[9];
    const float* warm     = (const float*)d_in[10];
    float* out = (float*)d_out;
    float* ws  = (float*)d_ws;

    float* h      = ws + OFF_H;
    int*   cnt    = (int*)(ws + OFF_CNT);
    float* slots  = ws + OFF_SLOTS;
    float* islots = ws + OFF_ISLOTS;
    int*   rs     = (int*)(ws + OFF_RS);
    int*   next   = (int*)(ws + OFF_NEXT);
    int*   srcq   = (int*)(ws + OFF_SRC);
    float* wq     = ws + OFF_WQ;
    int*   bs     = (int*)(ws + OFF_BS);

    hipMemsetAsync(cnt, 0, (BN + 512) * sizeof(float), stream);

    k_gemm<<<(NROWS + MT - 1) / MT, 256, 0, stream>>>(X_B, codebook, W, warm, h);
    k_hist<<<512, 256, 0, stream>>>(edge_dst, cnt);
    k_scan1<<<98, 1024, 0, stream>>>(cnt, rs, bs);
    k_scan2<<<1, 128, 0, stream>>>(bs);
    k_scan3<<<98, 1024, 0, stream>>>(rs, next, bs);
    k_slot<<<512, 256, 0, stream>>>(edge_dst, edge_src, ew, cidx, next, srcq, wq);
    k_aggregate<<<BN / 4, 256, 0, stream>>>(h, rs, srcq, wq, b, grad, X_B, out,
                                            slots, islots);
    k_finalize<<<1, 256, 0, stream>>>(slots, islots, warm, out + (size_t)BN * DD);
}

// Round 5
// 300.524 us; speedup vs baseline: 3.7322x; 1.0865x over previous
//
#include <hip/hip_runtime.h>

#define BN 100000
#define DD 128
#define EN 500000
#define NM 4096
#define NROWS (BN + NM)     // 104096
#define MT 128              // gemm row tile

// ---- ws layout (4-byte units) ----
#define OFF_H      0
#define LEN_H      ((size_t)NROWS * DD)           // 13,324,288
#define OFF_CNT    (LEN_H)                        // 100000 ints  (memset 0)
#define OFF_SLOTS  (OFF_CNT + BN)                 // 256 f xbnorm (memset 0)
#define OFF_ISLOTS (OFF_SLOTS + 256)              // 256 f info   (memset 0)
#define OFF_RS     (OFF_ISLOTS + 256)             // 100001 ints
#define OFF_NEXT   (OFF_RS + BN + 1)              // 100000 ints
#define OFF_EQ     ((OFF_NEXT + BN + 1) & ~(size_t)1)  // int2[EN], 8B-aligned
#define OFF_BS     (OFF_EQ + 2 * (size_t)EN)      // 128 ints

// ---------------- GEMM: h = [X_B; codebook*warm] @ W  (+ fused xb_norm) ----
__launch_bounds__(256)
__global__ void k_gemm(const float* __restrict__ X_B, const float* __restrict__ codebook,
                       const float* __restrict__ W, const float* __restrict__ warm,
                       float* __restrict__ h, float* __restrict__ slots) {
    __shared__ __align__(16) float XlT[32 * 128];   // [k][r]
    __shared__ __align__(16) float Wl[32 * 128];    // [k][c]
    __shared__ float ssq[128];                      // per-row sum of squares
    const int tid = threadIdx.x;
    const int tx = tid & 15, ty = tid >> 4;
    const int r0 = blockIdx.x * MT;
    const float wu = *warm;

    if (tid < 128) ssq[tid] = 0.f;

    float acc[8][8];
#pragma unroll
    for (int i = 0; i < 8; i++)
#pragma unroll
        for (int j = 0; j < 8; j++) acc[i][j] = 0.f;

    const float4* xb4 = (const float4*)X_B;
    const float4* cb4 = (const float4*)codebook;
    const float4* W4 = (const float4*)W;

    for (int kc = 0; kc < 4; kc++) {
        __syncthreads();
#pragma unroll
        for (int i = 0; i < 4; i++) {
            const int f = i * 256 + tid;
            const int r = f >> 3, kq = f & 7;
            const int R = r0 + r;
            float4 v = make_float4(0.f, 0.f, 0.f, 0.f);
            if (R < NROWS) {
                if (R < BN) {
                    v = xb4[(size_t)R * 32 + kc * 8 + kq];
                    atomicAdd(&ssq[r], v.x * v.x + v.y * v.y + v.z * v.z + v.w * v.w);
                } else {
                    v = cb4[(size_t)(R - BN) * 32 + kc * 8 + kq];
                    v.x *= wu; v.y *= wu; v.z *= wu; v.w *= wu;
                }
            }
            XlT[(kq * 4 + 0) * 128 + r] = v.x;
            XlT[(kq * 4 + 1) * 128 + r] = v.y;
            XlT[(kq * 4 + 2) * 128 + r] = v.z;
            XlT[(kq * 4 + 3) * 128 + r] = v.w;
        }
#pragma unroll
        for (int i = 0; i < 4; i++) {
            const int f = i * 256 + tid;
            ((float4*)Wl)[f] = W4[kc * 1024 + f];
        }
        __syncthreads();
#pragma unroll 4
        for (int k = 0; k < 32; k++) {
            const float4 a0 = *(const float4*)&XlT[k * 128 + ty * 4];
            const float4 a1 = *(const float4*)&XlT[k * 128 + 64 + ty * 4];
            const float4 b0 = *(const float4*)&Wl[k * 128 + tx * 4];
            const float4 b1 = *(const float4*)&Wl[k * 128 + 64 + tx * 4];
            const float ar[8] = {a0.x, a0.y, a0.z, a0.w, a1.x, a1.y, a1.z, a1.w};
            const float bc[8] = {b0.x, b0.y, b0.z, b0.w, b1.x, b1.y, b1.z, b1.w};
#pragma unroll
            for (int i = 0; i < 8; i++)
#pragma unroll
                for (int j = 0; j < 8; j++) acc[i][j] += ar[i] * bc[j];
        }
    }
#pragma unroll
    for (int i = 0; i < 8; i++) {
        const int R = r0 + ((i < 4) ? (ty * 4 + i) : (64 + ty * 4 + i - 4));
        if (R < NROWS) {
            float4 o0 = make_float4(acc[i][0], acc[i][1], acc[i][2], acc[i][3]);
            float4 o1 = make_float4(acc[i][4], acc[i][5], acc[i][6], acc[i][7]);
            *(float4*)&h[(size_t)R * DD + tx * 4] = o0;
            *(float4*)&h[(size_t)R * DD + 64 + tx * 4] = o1;
        }
    }
    // xb_norm: sqrt of per-row ssq, reduce 128 rows -> 2 atomics
    if (tid < 128) {
        const int R = r0 + tid;
        float v = (R < BN) ? sqrtf(ssq[tid]) : 0.f;
#pragma unroll
        for (int off = 32; off > 0; off >>= 1) v += __shfl_down(v, off);
        if ((tid & 63) == 0) unsafeAtomicAdd(&slots[blockIdx.x & 255], v);
    }
}

// ---------------- histogram by dst (int4) ----------------
__global__ void k_hist(const int* __restrict__ edge_dst, int* __restrict__ cnt) {
    const int e4 = blockIdx.x * blockDim.x + threadIdx.x;
    if (e4 < EN / 4) {
        const int4 d = ((const int4*)edge_dst)[e4];
        atomicAdd(&cnt[d.x], 1);
        atomicAdd(&cnt[d.y], 1);
        atomicAdd(&cnt[d.z], 1);
        atomicAdd(&cnt[d.w], 1);
    }
}

// ---------------- scan phase 1 ----------------
__launch_bounds__(1024)
__global__ void k_scan1(const int* __restrict__ cnt, int* __restrict__ rs,
                        int* __restrict__ bs) {
    __shared__ int sd[1024];
    const int t = threadIdx.x;
    const int i = blockIdx.x * 1024 + t;
    int v = (i < BN) ? cnt[i] : 0;
    sd[t] = v;
    __syncthreads();
    for (int off = 1; off < 1024; off <<= 1) {
        int x = (t >= off) ? sd[t - off] : 0;
        __syncthreads();
        sd[t] += x;
        __syncthreads();
    }
    if (i < BN) rs[i] = sd[t] - v;
    if (t == 0) bs[blockIdx.x] = sd[1023];
}

// ---------------- scan phase 2 ----------------
__global__ void k_scan2(int* __restrict__ bs) {
    __shared__ int sd[128];
    const int t = threadIdx.x;
    int v = (t < 98) ? bs[t] : 0;
    sd[t] = v;
    __syncthreads();
    for (int off = 1; off < 128; off <<= 1) {
        int x = (t >= off) ? sd[t - off] : 0;
        __syncthreads();
        sd[t] += x;
        __syncthreads();
    }
    bs[t] = sd[t] - v;
}

// ---------------- scan phase 3 ----------------
__launch_bounds__(1024)
__global__ void k_scan3(int* __restrict__ rs, int* __restrict__ next,
                        const int* __restrict__ bs) {
    const int i = blockIdx.x * 1024 + threadIdx.x;
    if (i < BN) {
        int v = rs[i] + bs[blockIdx.x];
        rs[i] = v;
        next[i] = v;
    }
    if (i == 0) rs[BN] = EN;
}

// ---------------- slot-scatter edges into CSR order (packed int2) --------
__global__ void k_slot(const int* __restrict__ edge_dst, const int* __restrict__ edge_src,
                       const float* __restrict__ ew, const int* __restrict__ cidx,
                       int* __restrict__ next, int2* __restrict__ eq) {
    for (int e = blockIdx.x * blockDim.x + threadIdx.x; e < EN;
         e += gridDim.x * blockDim.x) {
        const int d = edge_dst[e];
        const int s = edge_src[e];
        const int p = atomicAdd(&next[d], 1);
        const int se = (s < BN) ? s : (BN + cidx[s]);
        eq[p] = make_int2(se, __float_as_int(ew[e]));
    }
}

// ---------------- fused aggregate + info ----------------
// one wave per row; edge list preloaded cooperatively (1 vector load),
// shfl-broadcast, branchless grad gather (clamped hot index), 4x unroll.
__launch_bounds__(256)
__global__ void k_aggregate(const float* __restrict__ h, const int* __restrict__ rs,
                            const int2* __restrict__ eq,
                            const float* __restrict__ b, const float* __restrict__ grad,
                            float* __restrict__ out, float* __restrict__ islots) {
    const int lane = threadIdx.x & 63;
    const int wave = threadIdx.x >> 6;
    const int row = blockIdx.x * 4 + wave;   // grid 25000
    const float2* h2 = (const float2*)h;
    const float2* g2 = (const float2*)grad;

    // bias.grad term: one grad element per thread for first 2048 blocks
    float myinfo = 0.f;
    {
        const int gid = blockIdx.x * 256 + threadIdx.x;
        if (gid < NM * DD) myinfo = b[gid & 127] * grad[gid];
    }

    const int s0 = rs[row], s1 = rs[row + 1];
    const int cnt = s1 - s0;

    // preload: h[row] (for info), bias, and this row's edges (one load/lane)
    const float2 hd = h2[(size_t)row * 64 + lane];
    float2 acc = ((const float2*)b)[lane];
    int sv = 0; float wv = 0.f;
    if (lane < cnt) {
        const int2 e = eq[s0 + lane];
        sv = e.x; wv = __int_as_float(e.y);
    }

    float2 gacc = make_float2(0.f, 0.f);
    const int nb = (cnt < 64) ? cnt : 64;
    int i = 0;
    for (; i + 4 <= nb; i += 4) {
        const int sr0 = __shfl(sv, i),     sr1 = __shfl(sv, i + 1);
        const int sr2 = __shfl(sv, i + 2), sr3 = __shfl(sv, i + 3);
        const float w0 = __shfl(wv, i),     w1 = __shfl(wv, i + 1);
        const float w2 = __shfl(wv, i + 2), w3 = __shfl(wv, i + 3);
        const float2 h0 = h2[(size_t)sr0 * 64 + lane];
        const float2 h1 = h2[(size_t)sr1 * 64 + lane];
        const float2 hh2 = h2[(size_t)sr2 * 64 + lane];
        const float2 h3 = h2[(size_t)sr3 * 64 + lane];
        const int m0 = sr0 - BN, m1 = sr1 - BN, m2 = sr2 - BN, m3 = sr3 - BN;
        const float2 g0 = g2[(size_t)max(m0, 0) * 64 + lane];
        const float2 g1 = g2[(size_t)max(m1, 0) * 64 + lane];
        const float2 g2v = g2[(size_t)max(m2, 0) * 64 + lane];
        const float2 g3 = g2[(size_t)max(m3, 0) * 64 + lane];
        acc.x += w0 * h0.x + w1 * h1.x + w2 * hh2.x + w3 * h3.x;
        acc.y += w0 * h0.y + w1 * h1.y + w2 * hh2.y + w3 * h3.y;
        const float gw0 = (m0 >= 0) ? w0 : 0.f, gw1 = (m1 >= 0) ? w1 : 0.f;
        const float gw2 = (m2 >= 0) ? w2 : 0.f, gw3 = (m3 >= 0) ? w3 : 0.f;
        gacc.x += gw0 * g0.x + gw1 * g1.x + gw2 * g2v.x + gw3 * g3.x;
        gacc.y += gw0 * g0.y + gw1 * g1.y + gw2 * g2v.y + gw3 * g3.y;
    }
    for (; i < nb; i++) {
        const int sr = __shfl(sv, i);
        const float w = __shfl(wv, i);
        const float2 hv = h2[(size_t)sr * 64 + lane];
        acc.x += w * hv.x; acc.y += w * hv.y;
        const int m = sr - BN;
        const float2 gv = g2[(size_t)max(m, 0) * 64 + lane];
        const float gw = (m >= 0) ? w : 0.f;
        gacc.x += gw * gv.x; gacc.y += gw * gv.y;
    }
    // rare fallback: rows with >64 edges
    for (int j = s0 + 64; j < s1; j++) {
        const int2 e = eq[j];
        const int sr = e.x; const float w = __int_as_float(e.y);
        const float2 hv = h2[(size_t)sr * 64 + lane];
        acc.x += w * hv.x; acc.y += w * hv.y;
        const int m = sr - BN;
        const float2 gv = g2[(size_t)max(m, 0) * 64 + lane];
        const float gw = (m >= 0) ? w : 0.f;
        gacc.x += gw * gv.x; gacc.y += gw * gv.y;
    }

    ((float2*)out)[(size_t)row * 64 + lane] = acc;
    myinfo += hd.x * gacc.x + hd.y * gacc.y;
#pragma unroll
    for (int off = 32; off > 0; off >>= 1) myinfo += __shfl_down(myinfo, off);
    __shared__ float li[4];
    if (lane == 0) li[wave] = myinfo;
    __syncthreads();
    if (threadIdx.x == 0)
        unsafeAtomicAdd(&islots[blockIdx.x & 255], li[0] + li[1] + li[2] + li[3]);
}

// ---------------- finalize scalars ----------------
__global__ void k_finalize(const float* __restrict__ slots, const float* __restrict__ islots,
                           const float* __restrict__ warm, float* __restrict__ out_tail) {
    float v = slots[threadIdx.x];
    float u = islots[threadIdx.x];
#pragma unroll
    for (int off = 32; off > 0; off >>= 1) {
        v += __shfl_down(v, off);
        u += __shfl_down(u, off);
    }
    __shared__ float lv[4], lu[4];
    if ((threadIdx.x & 63) == 0) { lv[threadIdx.x >> 6] = v; lu[threadIdx.x >> 6] = u; }
    __syncthreads();
    if (threadIdx.x == 0) {
        out_tail[0] = (lv[0] + lv[1] + lv[2] + lv[3]) / (float)BN;
        out_tail[1] = (lu[0] + lu[1] + lu[2] + lu[3]) * warm[0];
    }
}

extern "C" void kernel_launch(void* const* d_in, const int* in_sizes, int n_in,
                              void* d_out, int out_size, void* d_ws, size_t ws_size,
                              hipStream_t stream) {
    const float* X_B      = (const float*)d_in[0];
    const int*   edge_dst = (const int*)d_in[1];
    const int*   edge_src = (const int*)d_in[2];
    const float* ew       = (const float*)d_in[3];
    const int*   cidx     = (const int*)d_in[5];
    const float* codebook = (const float*)d_in[6];
    const float* grad     = (const float*)d_in[7];
    const float* W        = (const float*)d_in[8];
    const float* b        = (const float*)d_in[9];
    const float* warm     = (const float*)d_in[10];
    float* out = (float*)d_out;
    float* ws  = (float*)d_ws;

    float* h      = ws + OFF_H;
    int*   cnt    = (int*)(ws + OFF_CNT);
    float* slots  = ws + OFF_SLOTS;
    float* islots = ws + OFF_ISLOTS;
    int*   rs     = (int*)(ws + OFF_RS);
    int*   next   = (int*)(ws + OFF_NEXT);
    int2*  eq     = (int2*)(ws + OFF_EQ);
    int*   bs     = (int*)(ws + OFF_BS);

    hipMemsetAsync(cnt, 0, (BN + 512) * sizeof(float), stream);

    k_gemm<<<(NROWS + MT - 1) / MT, 256, 0, stream>>>(X_B, codebook, W, warm, h, slots);
    k_hist<<<(EN / 4 + 255) / 256, 256, 0, stream>>>(edge_dst, cnt);
    k_scan1<<<98, 1024, 0, stream>>>(cnt, rs, bs);
    k_scan2<<<1, 128, 0, stream>>>(bs);
    k_scan3<<<98, 1024, 0, stream>>>(rs, next, bs);
    k_slot<<<512, 256, 0, stream>>>(edge_dst, edge_src, ew, cidx, next, eq);
    k_aggregate<<<BN / 4, 256, 0, stream>>>(h, rs, eq, b, grad, out, islots);
    k_finalize<<<1, 256, 0, stream>>>(slots, islots, warm, out + (size_t)BN * DD);
}

// Round 6
// 284.840 us; speedup vs baseline: 3.9377x; 1.0551x over previous
//
#include <hip/hip_runtime.h>

#define BN 100000
#define DD 128
#define EN 500000
#define NM 4096
#define NROWS (BN + NM)     // 104096
#define MT 128              // gemm row tile
#define XLP 132             // padded leading dim for XlT (breaks 8-way conflicts)

// ---- ws layout (4-byte units) ----
#define OFF_H      0
#define LEN_H      ((size_t)NROWS * DD)           // 13,324,288
#define OFF_CNT    (LEN_H)                        // 100000 ints  (memset 0)
#define OFF_SLOTS  (OFF_CNT + BN)                 // 256 f xbnorm (memset 0)
#define OFF_ISLOTS (OFF_SLOTS + 256)              // 256 f info   (memset 0)
#define OFF_RS     (OFF_ISLOTS + 256)             // 100001 ints
#define OFF_NEXT   (OFF_RS + BN + 1)              // 100000 ints
#define OFF_EQ     ((OFF_NEXT + BN + 1) & ~(size_t)1)  // int2[EN], 8B-aligned
#define OFF_BS     (OFF_EQ + 2 * (size_t)EN)      // 128 ints

// ---------------- GEMM: h = [X_B; codebook*warm] @ W  (+ fused xb_norm) ----
// xb_norm via per-thread register partials + shfl segmented reduce: NO LDS
// atomics (they collapsed VGPR alloc 136->68 and cost 30us in round 5).
__launch_bounds__(256)
__global__ void k_gemm(const float* __restrict__ X_B, const float* __restrict__ codebook,
                       const float* __restrict__ W, const float* __restrict__ warm,
                       float* __restrict__ h, float* __restrict__ slots) {
    __shared__ __align__(16) float XlT[32 * XLP];   // [k][r], padded
    __shared__ __align__(16) float Wl[32 * 128];    // [k][c]
    const int tid = threadIdx.x;
    const int tx = tid & 15, ty = tid >> 4;
    const int r0 = blockIdx.x * MT;
    const float wu = *warm;

    float acc[8][8];
#pragma unroll
    for (int i = 0; i < 8; i++)
#pragma unroll
        for (int j = 0; j < 8; j++) acc[i][j] = 0.f;

    float part[4] = {0.f, 0.f, 0.f, 0.f};   // xb_norm partials (row = (i*256+tid)>>3)

    const float4* xb4 = (const float4*)X_B;
    const float4* cb4 = (const float4*)codebook;
    const float4* W4 = (const float4*)W;

    for (int kc = 0; kc < 4; kc++) {
        __syncthreads();
#pragma unroll
        for (int i = 0; i < 4; i++) {
            const int f = i * 256 + tid;
            const int r = f >> 3, kq = f & 7;
            const int R = r0 + r;
            float4 v = make_float4(0.f, 0.f, 0.f, 0.f);
            if (R < NROWS) {
                if (R < BN) {
                    v = xb4[(size_t)R * 32 + kc * 8 + kq];
                    part[i] += v.x * v.x + v.y * v.y + v.z * v.z + v.w * v.w;
                } else {
                    v = cb4[(size_t)(R - BN) * 32 + kc * 8 + kq];
                    v.x *= wu; v.y *= wu; v.z *= wu; v.w *= wu;
                }
            }
            XlT[(kq * 4 + 0) * XLP + r] = v.x;
            XlT[(kq * 4 + 1) * XLP + r] = v.y;
            XlT[(kq * 4 + 2) * XLP + r] = v.z;
            XlT[(kq * 4 + 3) * XLP + r] = v.w;
        }
#pragma unroll
        for (int i = 0; i < 4; i++) {
            const int f = i * 256 + tid;
            ((float4*)Wl)[f] = W4[kc * 1024 + f];
        }
        __syncthreads();
#pragma unroll 4
        for (int k = 0; k < 32; k++) {
            const float4 a0 = *(const float4*)&XlT[k * XLP + ty * 4];
            const float4 a1 = *(const float4*)&XlT[k * XLP + 64 + ty * 4];
            const float4 b0 = *(const float4*)&Wl[k * 128 + tx * 4];
            const float4 b1 = *(const float4*)&Wl[k * 128 + 64 + tx * 4];
            const float ar[8] = {a0.x, a0.y, a0.z, a0.w, a1.x, a1.y, a1.z, a1.w};
            const float bc[8] = {b0.x, b0.y, b0.z, b0.w, b1.x, b1.y, b1.z, b1.w};
#pragma unroll
            for (int i = 0; i < 8; i++)
#pragma unroll
                for (int j = 0; j < 8; j++) acc[i][j] += ar[i] * bc[j];
        }
    }
#pragma unroll
    for (int i = 0; i < 8; i++) {
        const int R = r0 + ((i < 4) ? (ty * 4 + i) : (64 + ty * 4 + i - 4));
        if (R < NROWS) {
            float4 o0 = make_float4(acc[i][0], acc[i][1], acc[i][2], acc[i][3]);
            float4 o1 = make_float4(acc[i][4], acc[i][5], acc[i][6], acc[i][7]);
            *(float4*)&h[(size_t)R * DD + tx * 4] = o0;
            *(float4*)&h[(size_t)R * DD + 64 + tx * 4] = o1;
        }
    }
    // xb_norm: sum part over the 8 kq-lanes of each row (segmented shfl_xor),
    // sqrt on kq==0 lane, then block reduce -> 1 atomic per wave.
    float local = 0.f;
#pragma unroll
    for (int i = 0; i < 4; i++) {
        float p = part[i];
        p += __shfl_xor(p, 1);
        p += __shfl_xor(p, 2);
        p += __shfl_xor(p, 4);
        const int R = r0 + ((i * 256 + tid) >> 3);
        if ((tid & 7) == 0 && R < BN) local += sqrtf(p);
    }
#pragma unroll
    for (int off = 32; off > 0; off >>= 1) local += __shfl_down(local, off);
    if ((tid & 63) == 0) unsafeAtomicAdd(&slots[blockIdx.x & 255], local);
}

// ---------------- histogram by dst (int4) ----------------
__global__ void k_hist(const int* __restrict__ edge_dst, int* __restrict__ cnt) {
    const int e4 = blockIdx.x * blockDim.x + threadIdx.x;
    if (e4 < EN / 4) {
        const int4 d = ((const int4*)edge_dst)[e4];
        atomicAdd(&cnt[d.x], 1);
        atomicAdd(&cnt[d.y], 1);
        atomicAdd(&cnt[d.z], 1);
        atomicAdd(&cnt[d.w], 1);
    }
}

// ---------------- scan phase 1 ----------------
__launch_bounds__(1024)
__global__ void k_scan1(const int* __restrict__ cnt, int* __restrict__ rs,
                        int* __restrict__ bs) {
    __shared__ int sd[1024];
    const int t = threadIdx.x;
    const int i = blockIdx.x * 1024 + t;
    int v = (i < BN) ? cnt[i] : 0;
    sd[t] = v;
    __syncthreads();
    for (int off = 1; off < 1024; off <<= 1) {
        int x = (t >= off) ? sd[t - off] : 0;
        __syncthreads();
        sd[t] += x;
        __syncthreads();
    }
    if (i < BN) rs[i] = sd[t] - v;
    if (t == 0) bs[blockIdx.x] = sd[1023];
}

// ---------------- scan phase 2 ----------------
__global__ void k_scan2(int* __restrict__ bs) {
    __shared__ int sd[128];
    const int t = threadIdx.x;
    int v = (t < 98) ? bs[t] : 0;
    sd[t] = v;
    __syncthreads();
    for (int off = 1; off < 128; off <<= 1) {
        int x = (t >= off) ? sd[t - off] : 0;
        __syncthreads();
        sd[t] += x;
        __syncthreads();
    }
    bs[t] = sd[t] - v;
}

// ---------------- scan phase 3 ----------------
__launch_bounds__(1024)
__global__ void k_scan3(int* __restrict__ rs, int* __restrict__ next,
                        const int* __restrict__ bs) {
    const int i = blockIdx.x * 1024 + threadIdx.x;
    if (i < BN) {
        int v = rs[i] + bs[blockIdx.x];
        rs[i] = v;
        next[i] = v;
    }
    if (i == 0) rs[BN] = EN;
}

// ---------------- slot-scatter edges into CSR order (packed int2) --------
__global__ void k_slot(const int* __restrict__ edge_dst, const int* __restrict__ edge_src,
                       const float* __restrict__ ew, const int* __restrict__ cidx,
                       int* __restrict__ next, int2* __restrict__ eq) {
    for (int e = blockIdx.x * blockDim.x + threadIdx.x; e < EN;
         e += gridDim.x * blockDim.x) {
        const int d = edge_dst[e];
        const int s = edge_src[e];
        const int p = atomicAdd(&next[d], 1);
        const int se = (s < BN) ? s : (BN + cidx[s]);
        eq[p] = make_int2(se, __float_as_int(ew[e]));
    }
}

// ---------------- fused aggregate + info ----------------
__launch_bounds__(256)
__global__ void k_aggregate(const float* __restrict__ h, const int* __restrict__ rs,
                            const int2* __restrict__ eq,
                            const float* __restrict__ b, const float* __restrict__ grad,
                            float* __restrict__ out, float* __restrict__ islots) {
    const int lane = threadIdx.x & 63;
    const int wave = threadIdx.x >> 6;
    const int row = blockIdx.x * 4 + wave;   // grid 25000
    const float2* h2 = (const float2*)h;
    const float2* g2 = (const float2*)grad;

    float myinfo = 0.f;
    {
        const int gid = blockIdx.x * 256 + threadIdx.x;
        if (gid < NM * DD) myinfo = b[gid & 127] * grad[gid];
    }

    const int s0 = rs[row], s1 = rs[row + 1];
    const int cnt = s1 - s0;

    const float2 hd = h2[(size_t)row * 64 + lane];
    float2 acc = ((const float2*)b)[lane];
    int sv = 0; float wv = 0.f;
    if (lane < cnt) {
        const int2 e = eq[s0 + lane];
        sv = e.x; wv = __int_as_float(e.y);
    }

    float2 gacc = make_float2(0.f, 0.f);
    const int nb = (cnt < 64) ? cnt : 64;
    int i = 0;
    for (; i + 4 <= nb; i += 4) {
        const int sr0 = __shfl(sv, i),     sr1 = __shfl(sv, i + 1);
        const int sr2 = __shfl(sv, i + 2), sr3 = __shfl(sv, i + 3);
        const float w0 = __shfl(wv, i),     w1 = __shfl(wv, i + 1);
        const float w2 = __shfl(wv, i + 2), w3 = __shfl(wv, i + 3);
        const float2 h0 = h2[(size_t)sr0 * 64 + lane];
        const float2 h1 = h2[(size_t)sr1 * 64 + lane];
        const float2 hh2 = h2[(size_t)sr2 * 64 + lane];
        const float2 h3 = h2[(size_t)sr3 * 64 + lane];
        const int m0 = sr0 - BN, m1 = sr1 - BN, m2 = sr2 - BN, m3 = sr3 - BN;
        const float2 g0 = g2[(size_t)max(m0, 0) * 64 + lane];
        const float2 g1 = g2[(size_t)max(m1, 0) * 64 + lane];
        const float2 g2v = g2[(size_t)max(m2, 0) * 64 + lane];
        const float2 g3 = g2[(size_t)max(m3, 0) * 64 + lane];
        acc.x += w0 * h0.x + w1 * h1.x + w2 * hh2.x + w3 * h3.x;
        acc.y += w0 * h0.y + w1 * h1.y + w2 * hh2.y + w3 * h3.y;
        const float gw0 = (m0 >= 0) ? w0 : 0.f, gw1 = (m1 >= 0) ? w1 : 0.f;
        const float gw2 = (m2 >= 0) ? w2 : 0.f, gw3 = (m3 >= 0) ? w3 : 0.f;
        gacc.x += gw0 * g0.x + gw1 * g1.x + gw2 * g2v.x + gw3 * g3.x;
        gacc.y += gw0 * g0.y + gw1 * g1.y + gw2 * g2v.y + gw3 * g3.y;
    }
    for (; i < nb; i++) {
        const int sr = __shfl(sv, i);
        const float w = __shfl(wv, i);
        const float2 hv = h2[(size_t)sr * 64 + lane];
        acc.x += w * hv.x; acc.y += w * hv.y;
        const int m = sr - BN;
        const float2 gv = g2[(size_t)max(m, 0) * 64 + lane];
        const float gw = (m >= 0) ? w : 0.f;
        gacc.x += gw * gv.x; gacc.y += gw * gv.y;
    }
    for (int j = s0 + 64; j < s1; j++) {
        const int2 e = eq[j];
        const int sr = e.x; const float w = __int_as_float(e.y);
        const float2 hv = h2[(size_t)sr * 64 + lane];
        acc.x += w * hv.x; acc.y += w * hv.y;
        const int m = sr - BN;
        const float2 gv = g2[(size_t)max(m, 0) * 64 + lane];
        const float gw = (m >= 0) ? w : 0.f;
        gacc.x += gw * gv.x; gacc.y += gw * gv.y;
    }

    ((float2*)out)[(size_t)row * 64 + lane] = acc;
    myinfo += hd.x * gacc.x + hd.y * gacc.y;
#pragma unroll
    for (int off = 32; off > 0; off >>= 1) myinfo += __shfl_down(myinfo, off);
    __shared__ float li[4];
    if (lane == 0) li[wave] = myinfo;
    __syncthreads();
    if (threadIdx.x == 0)
        unsafeAtomicAdd(&islots[blockIdx.x & 255], li[0] + li[1] + li[2] + li[3]);
}

// ---------------- finalize scalars ----------------
__global__ void k_finalize(const float* __restrict__ slots, const float* __restrict__ islots,
                           const float* __restrict__ warm, float* __restrict__ out_tail) {
    float v = slots[threadIdx.x];
    float u = islots[threadIdx.x];
#pragma unroll
    for (int off = 32; off > 0; off >>= 1) {
        v += __shfl_down(v, off);
        u += __shfl_down(u, off);
    }
    __shared__ float lv[4], lu[4];
    if ((threadIdx.x & 63) == 0) { lv[threadIdx.x >> 6] = v; lu[threadIdx.x >> 6] = u; }
    __syncthreads();
    if (threadIdx.x == 0) {
        out_tail[0] = (lv[0] + lv[1] + lv[2] + lv[3]) / (float)BN;
        out_tail[1] = (lu[0] + lu[1] + lu[2] + lu[3]) * warm[0];
    }
}

extern "C" void kernel_launch(void* const* d_in, const int* in_sizes, int n_in,
                              void* d_out, int out_size, void* d_ws, size_t ws_size,
                              hipStream_t stream) {
    const float* X_B      = (const float*)d_in[0];
    const int*   edge_dst = (const int*)d_in[1];
    const int*   edge_src = (const int*)d_in[2];
    const float* ew       = (const float*)d_in[3];
    const int*   cidx     = (const int*)d_in[5];
    const float* codebook = (const float*)d_in[6];
    const float* grad     = (const float*)d_in[7];
    const float* W        = (const float*)d_in[8];
    const float* b        = (const float*)d_in[9];
    const float* warm     = (const float*)d_in[10];
    float* out = (float*)d_out;
    float* ws  = (float*)d_ws;

    float* h      = ws + OFF_H;
    int*   cnt    = (int*)(ws + OFF_CNT);
    float* slots  = ws + OFF_SLOTS;
    float* islots = ws + OFF_ISLOTS;
    int*   rs     = (int*)(ws + OFF_RS);
    int*   next   = (int*)(ws + OFF_NEXT);
    int2*  eq     = (int2*)(ws + OFF_EQ);
    int*   bs     = (int*)(ws + OFF_BS);

    hipMemsetAsync(cnt, 0, (BN + 512) * sizeof(float), stream);

    k_gemm<<<(NROWS + MT - 1) / MT, 256, 0, stream>>>(X_B, codebook, W, warm, h, slots);
    k_hist<<<(EN / 4 + 255) / 256, 256, 0, stream>>>(edge_dst, cnt);
    k_scan1<<<98, 1024, 0, stream>>>(cnt, rs, bs);
    k_scan2<<<1, 128, 0, stream>>>(bs);
    k_scan3<<<98, 1024, 0, stream>>>(rs, next, bs);
    k_slot<<<512, 256, 0, stream>>>(edge_dst, edge_src, ew, cidx, next, eq);
    k_aggregate<<<BN / 4, 256, 0, stream>>>(h, rs, eq, b, grad, out, islots);
    k_finalize<<<1, 256, 0, stream>>>(slots, islots, warm, out + (size_t)BN * DD);
}